// Round 1
// baseline (1047.615 us; speedup 1.0000x reference)
//
#include <hip/hip_runtime.h>

#define NN 100000
#define EE 3200000
#define FIN 512
#define HH 16
#define CC 40

// ---------------- edge dtype detector ----------------
// If edge_index is int64, every odd 32-bit word (high word) of the first 512
// words is 0. If int32, words are random values in [0,100000) -> almost all nonzero.
__global__ void k_detect(const int* __restrict__ ei, int* __restrict__ flag) {
    __shared__ int nz;
    int t = threadIdx.x;
    if (t == 0) nz = 0;
    __syncthreads();
    if (ei[2 * t + 1] != 0) atomicAdd(&nz, 1);
    __syncthreads();
    if (t == 0) flag[0] = (nz == 0) ? 1 : 0;  // 1 => int64 layout
}

__global__ void k_degcount(const int* __restrict__ ei, const int* __restrict__ flag,
                           int* __restrict__ deg) {
    int e = blockIdx.x * blockDim.x + threadIdx.x;
    if (e >= EE) return;
    int is64 = flag[0];
    int col = is64 ? ei[2 * (EE + e)] : ei[EE + e];
    atomicAdd(&deg[col], 1);
}

__global__ void k_dinv(const int* __restrict__ deg, float* __restrict__ dinv) {
    int i = blockIdx.x * blockDim.x + threadIdx.x;
    if (i >= NN) return;
    dinv[i] = rsqrtf((float)(deg[i] + 1));  // +1 self loop, always > 0
}

// ---------------- exclusive scan of deg -> ptr (3 kernels) ----------------
__global__ void k_scan1(const int* __restrict__ deg, int* __restrict__ bsum) {
    __shared__ int wsum[4];
    int t = threadIdx.x, lane = t & 63, wid = t >> 6;
    int base = blockIdx.x * 1024 + t * 4;
    int d0 = 0, d1 = 0, d2 = 0, d3 = 0;
    if (base + 3 < NN) {
        int4 v = *reinterpret_cast<const int4*>(deg + base);
        d0 = v.x; d1 = v.y; d2 = v.z; d3 = v.w;
    } else {
        if (base     < NN) d0 = deg[base];
        if (base + 1 < NN) d1 = deg[base + 1];
        if (base + 2 < NN) d2 = deg[base + 2];
    }
    int s = d0 + d1 + d2 + d3;
#pragma unroll
    for (int off = 32; off >= 1; off >>= 1) s += __shfl_xor(s, off);
    if (lane == 0) wsum[wid] = s;
    __syncthreads();
    if (t == 0) bsum[blockIdx.x] = wsum[0] + wsum[1] + wsum[2] + wsum[3];
}

__global__ void k_scan2(int* __restrict__ bsum, int* __restrict__ ptrN, int nb) {
    __shared__ int ws[2];
    int t = threadIdx.x, lane = t & 63, wid = t >> 6;
    int v = (t < nb) ? bsum[t] : 0;
    int orig = v;
#pragma unroll
    for (int off = 1; off < 64; off <<= 1) {
        int u = __shfl_up(v, off);
        if (lane >= off) v += u;
    }
    if (lane == 63) ws[wid] = v;
    __syncthreads();
    int add = (wid == 1) ? ws[0] : 0;
    int excl = v - orig + add;
    if (t < nb) bsum[t] = excl;
    if (t == 0) ptrN[0] = EE;  // ptr[N] = E
}

__global__ void k_scan3(const int* __restrict__ deg, const int* __restrict__ boff,
                        int* __restrict__ ptr, int* __restrict__ head) {
    __shared__ int wsum[4];
    int t = threadIdx.x, lane = t & 63, wid = t >> 6;
    int base = blockIdx.x * 1024 + t * 4;
    int d0 = 0, d1 = 0, d2 = 0, d3 = 0;
    if (base + 3 < NN) {
        int4 v = *reinterpret_cast<const int4*>(deg + base);
        d0 = v.x; d1 = v.y; d2 = v.z; d3 = v.w;
    } else {
        if (base     < NN) d0 = deg[base];
        if (base + 1 < NN) d1 = deg[base + 1];
        if (base + 2 < NN) d2 = deg[base + 2];
    }
    int ts = d0 + d1 + d2 + d3;
    int v = ts;
#pragma unroll
    for (int off = 1; off < 64; off <<= 1) {
        int u = __shfl_up(v, off);
        if (lane >= off) v += u;
    }
    if (lane == 63) wsum[wid] = v;
    __syncthreads();
    int woff = 0;
    for (int w0 = 0; w0 < wid; ++w0) woff += wsum[w0];
    int excl = v - ts + woff + boff[blockIdx.x];
    if (base     < NN) { ptr[base]     = excl; head[base]     = excl; } excl += d0;
    if (base + 1 < NN) { ptr[base + 1] = excl; head[base + 1] = excl; } excl += d1;
    if (base + 2 < NN) { ptr[base + 2] = excl; head[base + 2] = excl; } excl += d2;
    if (base + 3 < NN) { ptr[base + 3] = excl; head[base + 3] = excl; }
}

__global__ void k_scatter(const int* __restrict__ ei, const int* __restrict__ flag,
                          int* __restrict__ head, int* __restrict__ srcs) {
    int e = blockIdx.x * blockDim.x + threadIdx.x;
    if (e >= EE) return;
    int is64 = flag[0];
    int src = is64 ? ei[2 * e] : ei[e];
    int dst = is64 ? ei[2 * (EE + e)] : ei[EE + e];
    int p = atomicAdd(&head[dst], 1);
    srcs[p] = src;
}

// ---------------- g1 = (x @ W1) * dinv ----------------
__global__ void k_gemm1(const float* __restrict__ x, const float* __restrict__ W1,
                        const float* __restrict__ dinv, float* __restrict__ g1) {
    int i = blockIdx.x * blockDim.x + threadIdx.x;
    if (i >= NN) return;
    const float4* xr = reinterpret_cast<const float4*>(x + (size_t)i * FIN);
    float acc[HH];
#pragma unroll
    for (int f = 0; f < HH; ++f) acc[f] = 0.f;
#pragma unroll 1
    for (int kq = 0; kq < FIN / 4; ++kq) {
        float4 xv = xr[kq];
        const float* wr = W1 + kq * 4 * HH;  // uniform across lanes -> s_load
#pragma unroll
        for (int f = 0; f < HH; ++f) acc[f] = fmaf(xv.x, wr[f], acc[f]);
#pragma unroll
        for (int f = 0; f < HH; ++f) acc[f] = fmaf(xv.y, wr[HH + f], acc[f]);
#pragma unroll
        for (int f = 0; f < HH; ++f) acc[f] = fmaf(xv.z, wr[2 * HH + f], acc[f]);
#pragma unroll
        for (int f = 0; f < HH; ++f) acc[f] = fmaf(xv.w, wr[3 * HH + f], acc[f]);
    }
    float di = dinv[i];
    float4* o = reinterpret_cast<float4*>(g1 + (size_t)i * HH);
#pragma unroll
    for (int q = 0; q < HH / 4; ++q)
        o[q] = make_float4(acc[4 * q] * di, acc[4 * q + 1] * di,
                           acc[4 * q + 2] * di, acc[4 * q + 3] * di);
}

// ---------------- layer1 agg + relu + GEMM2 + scale -> g2 ----------------
__global__ void k_layer1(const float* __restrict__ g1, const int* __restrict__ ptr,
                         const int* __restrict__ srcs, const float* __restrict__ dinv,
                         const float* __restrict__ b1, const float* __restrict__ W2,
                         float* __restrict__ g2) {
    int i = blockIdx.x * blockDim.x + threadIdx.x;
    if (i >= NN) return;
    float acc[HH];
    {
        const float4* sp = reinterpret_cast<const float4*>(g1 + (size_t)i * HH);
#pragma unroll
        for (int q = 0; q < HH / 4; ++q) {
            float4 v = sp[q];
            acc[4 * q] = v.x; acc[4 * q + 1] = v.y; acc[4 * q + 2] = v.z; acc[4 * q + 3] = v.w;
        }
    }
    int e0 = ptr[i], e1 = ptr[i + 1];
    for (int e = e0; e < e1; ++e) {
        int s = srcs[e];
        const float4* gp = reinterpret_cast<const float4*>(g1 + (size_t)s * HH);
#pragma unroll
        for (int q = 0; q < HH / 4; ++q) {
            float4 v = gp[q];
            acc[4 * q] += v.x; acc[4 * q + 1] += v.y; acc[4 * q + 2] += v.z; acc[4 * q + 3] += v.w;
        }
    }
    float di = dinv[i];
    float a[HH];
#pragma unroll
    for (int f = 0; f < HH; ++f) {
        float t = fmaf(di, acc[f], b1[f]);
        a[f] = t > 0.f ? t : 0.f;
    }
    float h2[CC];
#pragma unroll
    for (int c = 0; c < CC; ++c) h2[c] = 0.f;
#pragma unroll
    for (int f = 0; f < HH; ++f) {
        float af = a[f];
        const float* w2r = W2 + f * CC;  // uniform -> s_load
#pragma unroll
        for (int c = 0; c < CC; ++c) h2[c] = fmaf(af, w2r[c], h2[c]);
    }
    float4* o = reinterpret_cast<float4*>(g2 + (size_t)i * CC);
#pragma unroll
    for (int q = 0; q < CC / 4; ++q)
        o[q] = make_float4(h2[4 * q] * di, h2[4 * q + 1] * di,
                           h2[4 * q + 2] * di, h2[4 * q + 3] * di);
}

// ---------------- layer2 agg + bias + log_softmax -> out ----------------
__global__ void k_layer2(const float* __restrict__ g2, const int* __restrict__ ptr,
                         const int* __restrict__ srcs, const float* __restrict__ dinv,
                         const float* __restrict__ b2, float* __restrict__ out) {
    int i = blockIdx.x * blockDim.x + threadIdx.x;
    if (i >= NN) return;
    float acc[CC];
    {
        const float4* sp = reinterpret_cast<const float4*>(g2 + (size_t)i * CC);
#pragma unroll
        for (int q = 0; q < CC / 4; ++q) {
            float4 v = sp[q];
            acc[4 * q] = v.x; acc[4 * q + 1] = v.y; acc[4 * q + 2] = v.z; acc[4 * q + 3] = v.w;
        }
    }
    int e0 = ptr[i], e1 = ptr[i + 1];
    for (int e = e0; e < e1; ++e) {
        int s = srcs[e];
        const float4* gp = reinterpret_cast<const float4*>(g2 + (size_t)s * CC);
#pragma unroll
        for (int q = 0; q < CC / 4; ++q) {
            float4 v = gp[q];
            acc[4 * q] += v.x; acc[4 * q + 1] += v.y; acc[4 * q + 2] += v.z; acc[4 * q + 3] += v.w;
        }
    }
    float di = dinv[i];
    float v[CC];
    float m = -3.0e38f;
#pragma unroll
    for (int c = 0; c < CC; ++c) {
        v[c] = fmaf(di, acc[c], b2[c]);
        m = fmaxf(m, v[c]);
    }
    float ssum = 0.f;
#pragma unroll
    for (int c = 0; c < CC; ++c) ssum += expf(v[c] - m);
    float l = logf(ssum);
    float4* o = reinterpret_cast<float4*>(out + (size_t)i * CC);
#pragma unroll
    for (int q = 0; q < CC / 4; ++q)
        o[q] = make_float4(v[4 * q] - m - l, v[4 * q + 1] - m - l,
                           v[4 * q + 2] - m - l, v[4 * q + 3] - m - l);
}

extern "C" void kernel_launch(void* const* d_in, const int* in_sizes, int n_in,
                              void* d_out, int out_size, void* d_ws, size_t ws_size,
                              hipStream_t stream) {
    const float* x  = (const float*)d_in[0];
    const int*   ei = (const int*)d_in[1];
    const float* W1 = (const float*)d_in[2];
    const float* b1 = (const float*)d_in[3];
    const float* W2 = (const float*)d_in[4];
    const float* b2 = (const float*)d_in[5];
    float* out = (float*)d_out;

    char* w = (char*)d_ws;
    auto alloc = [&](size_t bytes) {
        char* p = w;
        w += (bytes + 255) & ~(size_t)255;
        return p;
    };
    int*   flag = (int*)alloc(256);
    int*   deg  = (int*)alloc((size_t)NN * 4);
    float* dinv = (float*)alloc((size_t)NN * 4);
    int*   ptr  = (int*)alloc((size_t)(NN + 1) * 4);
    int*   head = (int*)alloc((size_t)NN * 4);
    int*   bsum = (int*)alloc(1024);
    int*   srcs = (int*)alloc((size_t)EE * 4);
    float* g1   = (float*)alloc((size_t)NN * HH * 4);
    float* g2   = (float*)alloc((size_t)NN * CC * 4);

    hipMemsetAsync(deg, 0, (size_t)NN * sizeof(int), stream);
    k_detect<<<1, 256, 0, stream>>>(ei, flag);
    k_degcount<<<(EE + 255) / 256, 256, 0, stream>>>(ei, flag, deg);
    k_dinv<<<(NN + 255) / 256, 256, 0, stream>>>(deg, dinv);
    int nb = (NN + 1023) / 1024;
    k_scan1<<<nb, 256, 0, stream>>>(deg, bsum);
    k_scan2<<<1, 128, 0, stream>>>(bsum, ptr + NN, nb);
    k_scan3<<<nb, 256, 0, stream>>>(deg, bsum, ptr, head);
    k_scatter<<<(EE + 255) / 256, 256, 0, stream>>>(ei, flag, head, srcs);
    k_gemm1<<<(NN + 255) / 256, 256, 0, stream>>>(x, W1, dinv, g1);
    k_layer1<<<(NN + 255) / 256, 256, 0, stream>>>(g1, ptr, srcs, dinv, b1, W2, g2);
    k_layer2<<<(NN + 255) / 256, 256, 0, stream>>>(g2, ptr, srcs, dinv, b2, out);
}

// Round 2
// 768.456 us; speedup vs baseline: 1.3633x; 1.3633x over previous
//
#include <hip/hip_runtime.h>

#define NN 100000
#define EE 3200000
#define FIN 512
#define HH 16
#define CC 40

#define SHIFT 9
#define BNODES 512                       // nodes per bucket
#define NB ((NN + BNODES - 1) / BNODES)  // 196 buckets
#define CH 4096                          // edges per binning chunk
#define TC ((EE + CH - 1) / CH)          // 782 chunks

// ---------------- edge dtype detector ----------------
// If edge_index is int64, every odd 32-bit word (high word) of the first 512
// words is 0. If int32, words are random in [0,100000) -> almost all nonzero.
__global__ void k_detect(const int* __restrict__ ei, int* __restrict__ flag) {
    __shared__ int nz;
    int t = threadIdx.x;
    if (t == 0) nz = 0;
    __syncthreads();
    if (ei[2 * t + 1] != 0) atomicAdd(&nz, 1);
    __syncthreads();
    if (t == 0) flag[0] = (nz == 0) ? 1 : 0;  // 1 => int64 layout
}

// ---------------- coarse bucket histogram ----------------
__global__ void k_hist(const int* __restrict__ ei, const int* __restrict__ flag,
                       int* __restrict__ bcnt) {
    __shared__ int h[NB];
    for (int i = threadIdx.x; i < NB; i += 256) h[i] = 0;
    __syncthreads();
    int is64 = flag[0];
    for (int e = blockIdx.x * 256 + threadIdx.x; e < EE; e += gridDim.x * 256) {
        int dst = is64 ? ei[2 * (EE + e)] : ei[EE + e];
        atomicAdd(&h[dst >> SHIFT], 1);
    }
    __syncthreads();
    for (int i = threadIdx.x; i < NB; i += 256)
        if (h[i]) atomicAdd(&bcnt[i], h[i]);
}

// ---------------- scan bucket counts -> base & head ----------------
__global__ void k_bscan(const int* __restrict__ bcnt, int* __restrict__ base,
                        int* __restrict__ head) {
    __shared__ int ws[4];
    int t = threadIdx.x, lane = t & 63, wid = t >> 6;
    int v = (t < NB) ? bcnt[t] : 0;
    int orig = v;
#pragma unroll
    for (int off = 1; off < 64; off <<= 1) {
        int u = __shfl_up(v, off);
        if (lane >= off) v += u;
    }
    if (lane == 63) ws[wid] = v;
    __syncthreads();
    int add = 0;
    for (int w = 0; w < wid; ++w) add += ws[w];
    int incl = v + add;
    int excl = incl - orig;
    if (t < NB) { base[t] = excl; head[t] = excl; }
    if (t == NB - 1) base[NB] = incl;  // == EE
}

// ---------------- bin edges into bucket-segmented (src,dst) pairs ----------------
__global__ void k_bin(const int* __restrict__ ei, const int* __restrict__ flag,
                      int* __restrict__ head, uint2* __restrict__ pairs) {
    __shared__ int h[NB];
    __shared__ int gbase[NB];
    __shared__ int lhead[NB];
    int t = threadIdx.x;
    int e0 = blockIdx.x * CH, e1 = min(EE, e0 + CH);
    int is64 = flag[0];
    for (int i = t; i < NB; i += 256) { h[i] = 0; lhead[i] = 0; }
    __syncthreads();
    for (int e = e0 + t; e < e1; e += 256) {
        int dst = is64 ? ei[2 * (EE + e)] : ei[EE + e];
        atomicAdd(&h[dst >> SHIFT], 1);
    }
    __syncthreads();
    // one global reservation per (block,bucket): block-private contiguous runs
    for (int i = t; i < NB; i += 256)
        gbase[i] = h[i] ? atomicAdd(&head[i], h[i]) : 0;
    __syncthreads();
    for (int e = e0 + t; e < e1; e += 256) {
        int src = is64 ? ei[2 * e] : ei[e];
        int dst = is64 ? ei[2 * (EE + e)] : ei[EE + e];
        int b = dst >> SHIFT;
        int p = gbase[b] + atomicAdd(&lhead[b], 1);
        pairs[p] = make_uint2((unsigned)src, (unsigned)dst);
    }
}

// ---------------- per-bucket: exact deg (LDS hist), ptr, dinv, CSR scatter ----------------
__global__ void k_build(const uint2* __restrict__ pairs, const int* __restrict__ base,
                        int* __restrict__ ptr, float* __restrict__ dinv,
                        int* __restrict__ srcs) {
    __shared__ int h[BNODES];
    __shared__ int lex[BNODES];
    __shared__ int ws[4];
    int b = blockIdx.x, t = threadIdx.x, lane = t & 63, wid = t >> 6;
    int node0 = b << SHIFT;
    int p0 = base[b], p1 = base[b + 1];
    for (int i = t; i < BNODES; i += 256) h[i] = 0;
    __syncthreads();
    for (int p = p0 + t; p < p1; p += 256) {
        uint2 pr = pairs[p];
        atomicAdd(&h[pr.y - node0], 1);
    }
    __syncthreads();
    // exclusive scan over 512 counts: thread t owns elements 2t, 2t+1
    int a0 = h[2 * t], a1 = h[2 * t + 1];
    int s = a0 + a1;
    int v = s;
#pragma unroll
    for (int off = 1; off < 64; off <<= 1) {
        int u = __shfl_up(v, off);
        if (lane >= off) v += u;
    }
    if (lane == 63) ws[wid] = v;
    __syncthreads();
    int add = 0;
    for (int w = 0; w < wid; ++w) add += ws[w];
    int incl = v + add;
    int e0 = incl - s;
    lex[2 * t] = e0;
    lex[2 * t + 1] = e0 + a0;
    __syncthreads();
    for (int i = t; i < BNODES; i += 256) {
        int n = node0 + i;
        if (n < NN) {
            ptr[n] = p0 + lex[i];
            dinv[n] = rsqrtf((float)(h[i] + 1));  // +1 self loop
        }
    }
    __syncthreads();
    // scatter src into exact CSR slots (writes confined to this block's region)
    for (int p = p0 + t; p < p1; p += 256) {
        uint2 pr = pairs[p];
        int pos = p0 + atomicAdd(&lex[pr.y - node0], 1);
        srcs[pos] = (int)pr.x;
    }
    if (b == 0 && t == 0) ptr[NN] = EE;
}

// ---------------- g1 = (x @ W1) * dinv ----------------
__global__ void k_gemm1(const float* __restrict__ x, const float* __restrict__ W1,
                        const float* __restrict__ dinv, float* __restrict__ g1) {
    int i = blockIdx.x * blockDim.x + threadIdx.x;
    if (i >= NN) return;
    const float4* xr = reinterpret_cast<const float4*>(x + (size_t)i * FIN);
    float acc[HH];
#pragma unroll
    for (int f = 0; f < HH; ++f) acc[f] = 0.f;
#pragma unroll 1
    for (int kq = 0; kq < FIN / 4; ++kq) {
        float4 xv = xr[kq];
        const float* wr = W1 + kq * 4 * HH;  // uniform across lanes -> s_load
#pragma unroll
        for (int f = 0; f < HH; ++f) acc[f] = fmaf(xv.x, wr[f], acc[f]);
#pragma unroll
        for (int f = 0; f < HH; ++f) acc[f] = fmaf(xv.y, wr[HH + f], acc[f]);
#pragma unroll
        for (int f = 0; f < HH; ++f) acc[f] = fmaf(xv.z, wr[2 * HH + f], acc[f]);
#pragma unroll
        for (int f = 0; f < HH; ++f) acc[f] = fmaf(xv.w, wr[3 * HH + f], acc[f]);
    }
    float di = dinv[i];
    float4* o = reinterpret_cast<float4*>(g1 + (size_t)i * HH);
#pragma unroll
    for (int q = 0; q < HH / 4; ++q)
        o[q] = make_float4(acc[4 * q] * di, acc[4 * q + 1] * di,
                           acc[4 * q + 2] * di, acc[4 * q + 3] * di);
}

// ---------------- layer1 agg + relu + GEMM2 + scale -> g2 ----------------
__global__ void k_layer1(const float* __restrict__ g1, const int* __restrict__ ptr,
                         const int* __restrict__ srcs, const float* __restrict__ dinv,
                         const float* __restrict__ b1, const float* __restrict__ W2,
                         float* __restrict__ g2) {
    int i = blockIdx.x * blockDim.x + threadIdx.x;
    if (i >= NN) return;
    float acc[HH];
    {
        const float4* sp = reinterpret_cast<const float4*>(g1 + (size_t)i * HH);
#pragma unroll
        for (int q = 0; q < HH / 4; ++q) {
            float4 v = sp[q];
            acc[4 * q] = v.x; acc[4 * q + 1] = v.y; acc[4 * q + 2] = v.z; acc[4 * q + 3] = v.w;
        }
    }
    int e0 = ptr[i], e1 = ptr[i + 1];
    for (int e = e0; e < e1; ++e) {
        int s = srcs[e];
        const float4* gp = reinterpret_cast<const float4*>(g1 + (size_t)s * HH);
#pragma unroll
        for (int q = 0; q < HH / 4; ++q) {
            float4 v = gp[q];
            acc[4 * q] += v.x; acc[4 * q + 1] += v.y; acc[4 * q + 2] += v.z; acc[4 * q + 3] += v.w;
        }
    }
    float di = dinv[i];
    float a[HH];
#pragma unroll
    for (int f = 0; f < HH; ++f) {
        float t = fmaf(di, acc[f], b1[f]);
        a[f] = t > 0.f ? t : 0.f;
    }
    float h2[CC];
#pragma unroll
    for (int c = 0; c < CC; ++c) h2[c] = 0.f;
#pragma unroll
    for (int f = 0; f < HH; ++f) {
        float af = a[f];
        const float* w2r = W2 + f * CC;  // uniform -> s_load
#pragma unroll
        for (int c = 0; c < CC; ++c) h2[c] = fmaf(af, w2r[c], h2[c]);
    }
    float4* o = reinterpret_cast<float4*>(g2 + (size_t)i * CC);
#pragma unroll
    for (int q = 0; q < CC / 4; ++q)
        o[q] = make_float4(h2[4 * q] * di, h2[4 * q + 1] * di,
                           h2[4 * q + 2] * di, h2[4 * q + 3] * di);
}

// ---------------- layer2 agg + bias + log_softmax -> out ----------------
__global__ void k_layer2(const float* __restrict__ g2, const int* __restrict__ ptr,
                         const int* __restrict__ srcs, const float* __restrict__ dinv,
                         const float* __restrict__ b2, float* __restrict__ out) {
    int i = blockIdx.x * blockDim.x + threadIdx.x;
    if (i >= NN) return;
    float acc[CC];
    {
        const float4* sp = reinterpret_cast<const float4*>(g2 + (size_t)i * CC);
#pragma unroll
        for (int q = 0; q < CC / 4; ++q) {
            float4 v = sp[q];
            acc[4 * q] = v.x; acc[4 * q + 1] = v.y; acc[4 * q + 2] = v.z; acc[4 * q + 3] = v.w;
        }
    }
    int e0 = ptr[i], e1 = ptr[i + 1];
    for (int e = e0; e < e1; ++e) {
        int s = srcs[e];
        const float4* gp = reinterpret_cast<const float4*>(g2 + (size_t)s * CC);
#pragma unroll
        for (int q = 0; q < CC / 4; ++q) {
            float4 v = gp[q];
            acc[4 * q] += v.x; acc[4 * q + 1] += v.y; acc[4 * q + 2] += v.z; acc[4 * q + 3] += v.w;
        }
    }
    float di = dinv[i];
    float v[CC];
    float m = -3.0e38f;
#pragma unroll
    for (int c = 0; c < CC; ++c) {
        v[c] = fmaf(di, acc[c], b2[c]);
        m = fmaxf(m, v[c]);
    }
    float ssum = 0.f;
#pragma unroll
    for (int c = 0; c < CC; ++c) ssum += expf(v[c] - m);
    float l = logf(ssum);
    float4* o = reinterpret_cast<float4*>(out + (size_t)i * CC);
#pragma unroll
    for (int q = 0; q < CC / 4; ++q)
        o[q] = make_float4(v[4 * q] - m - l, v[4 * q + 1] - m - l,
                           v[4 * q + 2] - m - l, v[4 * q + 3] - m - l);
}

extern "C" void kernel_launch(void* const* d_in, const int* in_sizes, int n_in,
                              void* d_out, int out_size, void* d_ws, size_t ws_size,
                              hipStream_t stream) {
    const float* x  = (const float*)d_in[0];
    const int*   ei = (const int*)d_in[1];
    const float* W1 = (const float*)d_in[2];
    const float* b1 = (const float*)d_in[3];
    const float* W2 = (const float*)d_in[4];
    const float* b2 = (const float*)d_in[5];
    float* out = (float*)d_out;

    char* w = (char*)d_ws;
    auto alloc = [&](size_t bytes) {
        char* p = w;
        w += (bytes + 255) & ~(size_t)255;
        return p;
    };
    int*   flag = (int*)alloc(256);
    int*   bcnt = (int*)alloc((size_t)NB * 4);
    int*   base = (int*)alloc((size_t)(NB + 1) * 4);
    int*   head = (int*)alloc((size_t)NB * 4);
    int*   ptr  = (int*)alloc((size_t)(NN + 1) * 4);
    float* dinv = (float*)alloc((size_t)NN * 4);
    int*   srcs = (int*)alloc((size_t)EE * 4);
    // pairs (25.6 MB) is dead after k_build; alias it with g1 (6.4 MB) + g2 (16 MB)
    char*  R    = alloc((size_t)EE * 8);
    uint2* pairs = (uint2*)R;
    float* g1   = (float*)R;
    float* g2   = (float*)(R + (size_t)NN * HH * 4);

    hipMemsetAsync(bcnt, 0, (size_t)NB * sizeof(int), stream);
    k_detect<<<1, 256, 0, stream>>>(ei, flag);
    k_hist<<<512, 256, 0, stream>>>(ei, flag, bcnt);
    k_bscan<<<1, 256, 0, stream>>>(bcnt, base, head);
    k_bin<<<TC, 256, 0, stream>>>(ei, flag, head, pairs);
    k_build<<<NB, 256, 0, stream>>>(pairs, base, ptr, dinv, srcs);
    k_gemm1<<<(NN + 255) / 256, 256, 0, stream>>>(x, W1, dinv, g1);
    k_layer1<<<(NN + 255) / 256, 256, 0, stream>>>(g1, ptr, srcs, dinv, b1, W2, g2);
    k_layer2<<<(NN + 255) / 256, 256, 0, stream>>>(g2, ptr, srcs, dinv, b2, out);
}

// Round 3
// 578.243 us; speedup vs baseline: 1.8117x; 1.3290x over previous
//
#include <hip/hip_runtime.h>

#define NN 100000
#define EE 3200000
#define FIN 512
#define HH 16
#define CC 40

#define SHIFT 9
#define BNODES 512                       // nodes per bucket
#define NB ((NN + BNODES - 1) / BNODES)  // 196 buckets
#define CH 4096                          // edges per binning chunk
#define TC ((EE + CH - 1) / CH)          // 782 chunks

// ---------------- edge dtype detector ----------------
__global__ void k_detect(const int* __restrict__ ei, int* __restrict__ flag) {
    __shared__ int nz;
    int t = threadIdx.x;
    if (t == 0) nz = 0;
    __syncthreads();
    if (ei[2 * t + 1] != 0) atomicAdd(&nz, 1);
    __syncthreads();
    if (t == 0) flag[0] = (nz == 0) ? 1 : 0;  // 1 => int64 layout
}

// ---------------- coarse bucket histogram ----------------
__global__ void k_hist(const int* __restrict__ ei, const int* __restrict__ flag,
                       int* __restrict__ bcnt) {
    __shared__ int h[NB];
    for (int i = threadIdx.x; i < NB; i += 256) h[i] = 0;
    __syncthreads();
    int is64 = flag[0];
    for (int e = blockIdx.x * 256 + threadIdx.x; e < EE; e += gridDim.x * 256) {
        int dst = is64 ? ei[2 * (EE + e)] : ei[EE + e];
        atomicAdd(&h[dst >> SHIFT], 1);
    }
    __syncthreads();
    for (int i = threadIdx.x; i < NB; i += 256)
        if (h[i]) atomicAdd(&bcnt[i], h[i]);
}

// ---------------- scan bucket counts -> base & head ----------------
__global__ void k_bscan(const int* __restrict__ bcnt, int* __restrict__ base,
                        int* __restrict__ head) {
    __shared__ int ws[4];
    int t = threadIdx.x, lane = t & 63, wid = t >> 6;
    int v = (t < NB) ? bcnt[t] : 0;
    int orig = v;
#pragma unroll
    for (int off = 1; off < 64; off <<= 1) {
        int u = __shfl_up(v, off);
        if (lane >= off) v += u;
    }
    if (lane == 63) ws[wid] = v;
    __syncthreads();
    int add = 0;
    for (int w = 0; w < wid; ++w) add += ws[w];
    int incl = v + add;
    int excl = incl - orig;
    if (t < NB) { base[t] = excl; head[t] = excl; }
    if (t == NB - 1) base[NB] = incl;  // == EE
}

// ---------------- bin edges into bucket-segmented (src,dst) pairs ----------------
__global__ void k_bin(const int* __restrict__ ei, const int* __restrict__ flag,
                      int* __restrict__ head, uint2* __restrict__ pairs) {
    __shared__ int h[NB];
    __shared__ int gbase[NB];
    __shared__ int lhead[NB];
    int t = threadIdx.x;
    int e0 = blockIdx.x * CH, e1 = min(EE, e0 + CH);
    int is64 = flag[0];
    for (int i = t; i < NB; i += 256) { h[i] = 0; lhead[i] = 0; }
    __syncthreads();
    for (int e = e0 + t; e < e1; e += 256) {
        int dst = is64 ? ei[2 * (EE + e)] : ei[EE + e];
        atomicAdd(&h[dst >> SHIFT], 1);
    }
    __syncthreads();
    for (int i = t; i < NB; i += 256)
        gbase[i] = h[i] ? atomicAdd(&head[i], h[i]) : 0;
    __syncthreads();
    for (int e = e0 + t; e < e1; e += 256) {
        int src = is64 ? ei[2 * e] : ei[e];
        int dst = is64 ? ei[2 * (EE + e)] : ei[EE + e];
        int b = dst >> SHIFT;
        int p = gbase[b] + atomicAdd(&lhead[b], 1);
        pairs[p] = make_uint2((unsigned)src, (unsigned)dst);
    }
}

// ---------------- per-bucket: exact deg, ptr, dinv, CSR scatter ----------------
__global__ void k_build(const uint2* __restrict__ pairs, const int* __restrict__ base,
                        int* __restrict__ ptr, float* __restrict__ dinv,
                        int* __restrict__ srcs) {
    __shared__ int h[BNODES];
    __shared__ int lex[BNODES];
    __shared__ int ws[4];
    int b = blockIdx.x, t = threadIdx.x, lane = t & 63, wid = t >> 6;
    int node0 = b << SHIFT;
    int p0 = base[b], p1 = base[b + 1];
    for (int i = t; i < BNODES; i += 256) h[i] = 0;
    __syncthreads();
    for (int p = p0 + t; p < p1; p += 256) {
        uint2 pr = pairs[p];
        atomicAdd(&h[pr.y - node0], 1);
    }
    __syncthreads();
    int a0 = h[2 * t], a1 = h[2 * t + 1];
    int s = a0 + a1;
    int v = s;
#pragma unroll
    for (int off = 1; off < 64; off <<= 1) {
        int u = __shfl_up(v, off);
        if (lane >= off) v += u;
    }
    if (lane == 63) ws[wid] = v;
    __syncthreads();
    int add = 0;
    for (int w = 0; w < wid; ++w) add += ws[w];
    int incl = v + add;
    int e0 = incl - s;
    lex[2 * t] = e0;
    lex[2 * t + 1] = e0 + a0;
    __syncthreads();
    for (int i = t; i < BNODES; i += 256) {
        int n = node0 + i;
        if (n < NN) {
            ptr[n] = p0 + lex[i];
            dinv[n] = rsqrtf((float)(h[i] + 1));  // +1 self loop
        }
    }
    __syncthreads();
    for (int p = p0 + t; p < p1; p += 256) {
        uint2 pr = pairs[p];
        int pos = p0 + atomicAdd(&lex[pr.y - node0], 1);
        srcs[pos] = (int)pr.x;
    }
    if (b == 0 && t == 0) ptr[NN] = EE;
}

// ---------------- g1 = (x @ W1) * dinv ----------------
__global__ void k_gemm1(const float* __restrict__ x, const float* __restrict__ W1,
                        const float* __restrict__ dinv, float* __restrict__ g1) {
    int i = blockIdx.x * blockDim.x + threadIdx.x;
    if (i >= NN) return;
    const float4* xr = reinterpret_cast<const float4*>(x + (size_t)i * FIN);
    float acc[HH];
#pragma unroll
    for (int f = 0; f < HH; ++f) acc[f] = 0.f;
#pragma unroll 1
    for (int kq = 0; kq < FIN / 4; ++kq) {
        float4 xv = xr[kq];
        const float* wr = W1 + kq * 4 * HH;  // uniform across lanes -> s_load
#pragma unroll
        for (int f = 0; f < HH; ++f) acc[f] = fmaf(xv.x, wr[f], acc[f]);
#pragma unroll
        for (int f = 0; f < HH; ++f) acc[f] = fmaf(xv.y, wr[HH + f], acc[f]);
#pragma unroll
        for (int f = 0; f < HH; ++f) acc[f] = fmaf(xv.z, wr[2 * HH + f], acc[f]);
#pragma unroll
        for (int f = 0; f < HH; ++f) acc[f] = fmaf(xv.w, wr[3 * HH + f], acc[f]);
    }
    float di = dinv[i];
    float4* o = reinterpret_cast<float4*>(g1 + (size_t)i * HH);
#pragma unroll
    for (int q = 0; q < HH / 4; ++q)
        o[q] = make_float4(acc[4 * q] * di, acc[4 * q + 1] * di,
                           acc[4 * q + 2] * di, acc[4 * q + 3] * di);
}

// ---------------- 16-dim aggregation, 4 threads per node ----------------
// agg1: z = di*(self+sum) + b1 ; g2h = di * relu(z)
__global__ void k_agg1(const float* __restrict__ g1, const int* __restrict__ ptr,
                       const int* __restrict__ srcs, const float* __restrict__ dinv,
                       const float* __restrict__ b1, float* __restrict__ g2h) {
    int t = blockIdx.x * blockDim.x + threadIdx.x;
    int node = t >> 2, q = t & 3;
    if (node >= NN) return;
    const float4* G = reinterpret_cast<const float4*>(g1);
    float4 a = G[node * 4 + q];  // self term
    float4 a1 = make_float4(0.f, 0.f, 0.f, 0.f);
    float4 a2 = make_float4(0.f, 0.f, 0.f, 0.f);
    float4 a3 = make_float4(0.f, 0.f, 0.f, 0.f);
    int e = ptr[node], e1 = ptr[node + 1];
    for (; e + 3 < e1; e += 4) {
        int s0 = srcs[e], s1 = srcs[e + 1], s2 = srcs[e + 2], s3 = srcs[e + 3];
        float4 v0 = G[s0 * 4 + q];
        float4 v1 = G[s1 * 4 + q];
        float4 v2 = G[s2 * 4 + q];
        float4 v3 = G[s3 * 4 + q];
        a.x += v0.x; a.y += v0.y; a.z += v0.z; a.w += v0.w;
        a1.x += v1.x; a1.y += v1.y; a1.z += v1.z; a1.w += v1.w;
        a2.x += v2.x; a2.y += v2.y; a2.z += v2.z; a2.w += v2.w;
        a3.x += v3.x; a3.y += v3.y; a3.z += v3.z; a3.w += v3.w;
    }
    for (; e < e1; ++e) {
        float4 v = G[srcs[e] * 4 + q];
        a.x += v.x; a.y += v.y; a.z += v.z; a.w += v.w;
    }
    a.x += a1.x + a2.x + a3.x;
    a.y += a1.y + a2.y + a3.y;
    a.z += a1.z + a2.z + a3.z;
    a.w += a1.w + a2.w + a3.w;
    float di = dinv[node];
    const float4 bb = reinterpret_cast<const float4*>(b1)[q];
    float4 r;
    r.x = fmaxf(fmaf(di, a.x, bb.x), 0.f) * di;
    r.y = fmaxf(fmaf(di, a.y, bb.y), 0.f) * di;
    r.z = fmaxf(fmaf(di, a.z, bb.z), 0.f) * di;
    r.w = fmaxf(fmaf(di, a.w, bb.w), 0.f) * di;
    reinterpret_cast<float4*>(g2h)[node * 4 + q] = r;
}

// agg2: s = self + sum (raw; di/W2/b2/softmax applied in k_out)
__global__ void k_agg2(const float* __restrict__ g2h, const int* __restrict__ ptr,
                       const int* __restrict__ srcs, float* __restrict__ sarr) {
    int t = blockIdx.x * blockDim.x + threadIdx.x;
    int node = t >> 2, q = t & 3;
    if (node >= NN) return;
    const float4* G = reinterpret_cast<const float4*>(g2h);
    float4 a = G[node * 4 + q];
    float4 a1 = make_float4(0.f, 0.f, 0.f, 0.f);
    float4 a2 = make_float4(0.f, 0.f, 0.f, 0.f);
    float4 a3 = make_float4(0.f, 0.f, 0.f, 0.f);
    int e = ptr[node], e1 = ptr[node + 1];
    for (; e + 3 < e1; e += 4) {
        int s0 = srcs[e], s1 = srcs[e + 1], s2 = srcs[e + 2], s3 = srcs[e + 3];
        float4 v0 = G[s0 * 4 + q];
        float4 v1 = G[s1 * 4 + q];
        float4 v2 = G[s2 * 4 + q];
        float4 v3 = G[s3 * 4 + q];
        a.x += v0.x; a.y += v0.y; a.z += v0.z; a.w += v0.w;
        a1.x += v1.x; a1.y += v1.y; a1.z += v1.z; a1.w += v1.w;
        a2.x += v2.x; a2.y += v2.y; a2.z += v2.z; a2.w += v2.w;
        a3.x += v3.x; a3.y += v3.y; a3.z += v3.z; a3.w += v3.w;
    }
    for (; e < e1; ++e) {
        float4 v = G[srcs[e] * 4 + q];
        a.x += v.x; a.y += v.y; a.z += v.z; a.w += v.w;
    }
    a.x += a1.x + a2.x + a3.x;
    a.y += a1.y + a2.y + a3.y;
    a.z += a1.z + a2.z + a3.z;
    a.w += a1.w + a2.w + a3.w;
    reinterpret_cast<float4*>(sarr)[node * 4 + q] = a;
}

// ---------------- node-local: y = di*(s@W2)+b2 ; out = log_softmax(y) ----------------
__global__ void k_out(const float* __restrict__ sarr, const float* __restrict__ dinv,
                      const float* __restrict__ W2, const float* __restrict__ b2,
                      float* __restrict__ out) {
    int i = blockIdx.x * blockDim.x + threadIdx.x;
    if (i >= NN) return;
    float s[HH];
    {
        const float4* sp = reinterpret_cast<const float4*>(sarr + (size_t)i * HH);
#pragma unroll
        for (int qk = 0; qk < HH / 4; ++qk) {
            float4 v = sp[qk];
            s[4 * qk] = v.x; s[4 * qk + 1] = v.y; s[4 * qk + 2] = v.z; s[4 * qk + 3] = v.w;
        }
    }
    float di = dinv[i];
    float y[CC];
#pragma unroll
    for (int c = 0; c < CC; ++c) y[c] = 0.f;
#pragma unroll
    for (int f = 0; f < HH; ++f) {
        float sf = s[f];
        const float* w2r = W2 + f * CC;  // uniform -> s_load
#pragma unroll
        for (int c = 0; c < CC; ++c) y[c] = fmaf(sf, w2r[c], y[c]);
    }
    float m = -3.0e38f;
#pragma unroll
    for (int c = 0; c < CC; ++c) {
        y[c] = fmaf(di, y[c], b2[c]);
        m = fmaxf(m, y[c]);
    }
    float ssum = 0.f;
#pragma unroll
    for (int c = 0; c < CC; ++c) ssum += expf(y[c] - m);
    float l = logf(ssum) + m;
    float4* o = reinterpret_cast<float4*>(out + (size_t)i * CC);
#pragma unroll
    for (int qk = 0; qk < CC / 4; ++qk)
        o[qk] = make_float4(y[4 * qk] - l, y[4 * qk + 1] - l,
                            y[4 * qk + 2] - l, y[4 * qk + 3] - l);
}

extern "C" void kernel_launch(void* const* d_in, const int* in_sizes, int n_in,
                              void* d_out, int out_size, void* d_ws, size_t ws_size,
                              hipStream_t stream) {
    const float* x  = (const float*)d_in[0];
    const int*   ei = (const int*)d_in[1];
    const float* W1 = (const float*)d_in[2];
    const float* b1 = (const float*)d_in[3];
    const float* W2 = (const float*)d_in[4];
    const float* b2 = (const float*)d_in[5];
    float* out = (float*)d_out;

    char* w = (char*)d_ws;
    auto alloc = [&](size_t bytes) {
        char* p = w;
        w += (bytes + 255) & ~(size_t)255;
        return p;
    };
    int*   flag = (int*)alloc(256);
    int*   bcnt = (int*)alloc((size_t)NB * 4);
    int*   base = (int*)alloc((size_t)(NB + 1) * 4);
    int*   head = (int*)alloc((size_t)NB * 4);
    int*   ptr  = (int*)alloc((size_t)(NN + 1) * 4);
    float* dinv = (float*)alloc((size_t)NN * 4);
    int*   srcs = (int*)alloc((size_t)EE * 4);
    // pairs (25.6 MB) dead after k_build; alias with g1/g2h/s (6.4 MB each)
    char*  R    = alloc((size_t)EE * 8);
    uint2* pairs = (uint2*)R;
    float* g1   = (float*)R;
    float* g2h  = (float*)(R + (size_t)NN * HH * 4);
    float* sarr = (float*)(R + (size_t)NN * HH * 8);

    hipMemsetAsync(bcnt, 0, (size_t)NB * sizeof(int), stream);
    k_detect<<<1, 256, 0, stream>>>(ei, flag);
    k_hist<<<512, 256, 0, stream>>>(ei, flag, bcnt);
    k_bscan<<<1, 256, 0, stream>>>(bcnt, base, head);
    k_bin<<<TC, 256, 0, stream>>>(ei, flag, head, pairs);
    k_build<<<NB, 256, 0, stream>>>(pairs, base, ptr, dinv, srcs);
    k_gemm1<<<(NN + 255) / 256, 256, 0, stream>>>(x, W1, dinv, g1);
    int nt = NN * 4;
    k_agg1<<<(nt + 255) / 256, 256, 0, stream>>>(g1, ptr, srcs, dinv, b1, g2h);
    k_agg2<<<(nt + 255) / 256, 256, 0, stream>>>(g2h, ptr, srcs, sarr);
    k_out<<<(NN + 255) / 256, 256, 0, stream>>>(sarr, dinv, W2, b2, out);
}